// Round 10
// baseline (192.237 us; speedup 1.0000x reference)
//
#include <hip/hip_runtime.h>
#include <hip/hip_bf16.h>

typedef unsigned short u16;
typedef signed char i8;
typedef __attribute__((ext_vector_type(4))) int   int4v;   // 16 x i8 MFMA A/B frag, or i32x4 C/D
typedef __attribute__((ext_vector_type(4))) float f32x4;

#define GLOBAL_AS __attribute__((address_space(1)))
#define LDS_AS    __attribute__((address_space(3)))

__device__ __forceinline__ void gload_lds16(const void* g, void* l) {
    // 16B/lane direct global->LDS (dest = wave-uniform base + lane*16)
    __builtin_amdgcn_global_load_lds((const GLOBAL_AS unsigned int*)g,
                                     (LDS_AS unsigned int*)l, 16, 0, 0);
}

// ---------------- x: f32 -> i8, per-row symmetric quant; inv_s[row] = rowmax/127 ----------------
__global__ __launch_bounds__(256) void quant_x_kernel(const float* __restrict__ X,
                                                      i8* __restrict__ Xq,
                                                      float* __restrict__ inv_s) {
    const int row = blockIdx.x;
    const int t   = threadIdx.x;
    const float4* src = (const float4*)(X + (size_t)row * 4096 + t * 16);
    float4 v0 = src[0], v1 = src[1], v2 = src[2], v3 = src[3];
    float vals[16] = {v0.x, v0.y, v0.z, v0.w, v1.x, v1.y, v1.z, v1.w,
                      v2.x, v2.y, v2.z, v2.w, v3.x, v3.y, v3.z, v3.w};
    float m = 0.f;
#pragma unroll
    for (int j = 0; j < 16; ++j) m = fmaxf(m, fabsf(vals[j]));
#pragma unroll
    for (int off = 32; off; off >>= 1) m = fmaxf(m, __shfl_xor(m, off));
    __shared__ float sm[4];
    if ((t & 63) == 0) sm[t >> 6] = m;
    __syncthreads();
    m = fmaxf(fmaxf(sm[0], sm[1]), fmaxf(sm[2], sm[3]));
    const float s = (m > 0.f) ? 127.0f / m : 0.f;
    uint4 packed;
    unsigned int* pw = (unsigned int*)&packed;
#pragma unroll
    for (int g = 0; g < 4; ++g) {
        unsigned int wd = 0;
#pragma unroll
        for (int j = 0; j < 4; ++j) {
            int q = (int)rintf(vals[g * 4 + j] * s);   // |q| <= 127 by construction
            wd |= ((unsigned int)(q & 255)) << (8 * j);
        }
        pw[g] = wd;
    }
    ((uint4*)(Xq + (size_t)row * 4096))[t] = packed;
    if (t == 0) inv_s[row] = m * (1.0f / 127.0f);
}

// ---------------- W: f32 [K][N] -> sign i8 (+-1), transposed to [N][K] ----------------
__global__ __launch_bounds__(256) void conv_w_kernel(const float* __restrict__ W,
                                                     i8* __restrict__ Wt) {
    __shared__ __attribute__((aligned(16))) i8 tile[64][80];   // [n_local][k_local], 80 = 5*16
    const int t  = threadIdx.x;
    const int k0 = (blockIdx.x & 63) * 64;
    const int n0 = (blockIdx.x >> 6) * 64;
#pragma unroll
    for (int i = 0; i < 4; ++i) {
        const int r = i * 16 + (t >> 4);      // k_local
        const int c = (t & 15) * 4;           // n_local
        float4 v = *(const float4*)&W[(size_t)(k0 + r) * 4096 + n0 + c];
        tile[c + 0][r] = (v.x >= 0.f) ? 1 : -1;
        tile[c + 1][r] = (v.y >= 0.f) ? 1 : -1;
        tile[c + 2][r] = (v.z >= 0.f) ? 1 : -1;
        tile[c + 3][r] = (v.w >= 0.f) ? 1 : -1;
    }
    __syncthreads();
    const int r = t >> 2;                     // n_local 0..63
    const int c = (t & 3) * 16;               // k_local 16B chunk
    *(int4*)&Wt[(size_t)(n0 + r) * 4096 + k0 + c] = *(const int4*)&tile[r][c];
}

// ---------------- GEMM: i8 256x256, BK=64; A global->reg (VMEM), B via LDS (r10) ----------------
// r6-r9 evidence: time = LDS-pipe + matrix-pipe SUM in every schedule (no overlap achievable
// at source level). Fix: move A-fragment traffic (2/3 of LDS reads) to the VMEM pipe as
// per-lane global->register loads prefetched one K-tile ahead (HK reg-staging pattern) —
// VMEM overlaps MFMA via counted vmcnt. LDS keeps only B (stage 16KB + 4 frag reads/iter).
// 4 B-buffers (64KB), body fence vmcnt(10) leaves exactly A(t+1)8 + Bstage(t+2)2 in flight.
// A regs double-buffered with static names (rule 20), loop unrolled x4 (buffer period).

#define BAR()        __builtin_amdgcn_s_barrier()
#define LGKM0M()     asm volatile("s_waitcnt lgkmcnt(0)" ::: "memory")
#define WAIT_VM10()  asm volatile("s_waitcnt vmcnt(10)" ::: "memory")
#define WAIT_VM2()   asm volatile("s_waitcnt vmcnt(2)" ::: "memory")

// stage one B K-tile slice for this wave (rows 32w..32w+31, 2 KB): 2 x gload_lds
#define STAGE_B(base, koff)                                                         \
    do {                                                                            \
        gload_lds16(BsrcT + (koff),         lds + (base) + wB);                     \
        gload_lds16(BsrcT + 65536 + (koff), lds + (base) + wB + 1024);              \
    } while (0)

// one K-tile body: t reads buf RB, stages B(t+2)->SB, loads A(t+1)->AN, MFMAs with AC
#define BODY(tt, RB, SB, AC, AN)                                                    \
    do {                                                                            \
        const int kA = (((tt) + 1) & 63) * 64;                                      \
        const int kB = (((tt) + 2) & 63) * 64;                                      \
        _Pragma("unroll") for (int mi = 0; mi < 8; ++mi)                            \
            AN[mi] = *(const int4v*)(Agl + aoff[mi] + kA);                          \
        STAGE_B(SB, kB);                                                            \
        _Pragma("unroll") for (int ni = 0; ni < 4; ++ni)                            \
            bf[ni] = *(const int4v*)(lds + (RB) + b_rd + ni * 1024);                \
        __builtin_amdgcn_s_setprio(1);                                              \
        _Pragma("unroll") for (int mi = 0; mi < 8; ++mi)                            \
        _Pragma("unroll") for (int ni = 0; ni < 4; ++ni)                            \
            acc[mi][ni] = __builtin_amdgcn_mfma_i32_16x16x64_i8(AC[mi], bf[ni],     \
                                                                acc[mi][ni], 0, 0, 0); \
        __builtin_amdgcn_s_setprio(0);                                              \
        WAIT_VM10();                                                                \
        LGKM0M();                                                                   \
        BAR();                                                                      \
    } while (0)

__global__ __launch_bounds__(512, 2) void gemm_bin_kernel(const i8* __restrict__ A,
                                                          const i8* __restrict__ Bt,
                                                          const float* __restrict__ bias,
                                                          const float* __restrict__ inv_s,
                                                          float* __restrict__ C) {
    __shared__ __attribute__((aligned(1024))) char lds[65536];   // 4 B-buffers x 16 KB

    const int bid = blockIdx.x;
    const int swz = (bid & 7) * 32 + (bid >> 3);   // XCD-aware, bijective (256 % 8 == 0)
    const int bm  = swz >> 4;                      // 16x16 tiles of 256
    const int bn  = swz & 15;

    const int tid = threadIdx.x;
    const int w   = tid >> 6;
    const int l   = tid & 63;
    const int wm  = w >> 2;                        // 2 M-waves
    const int wn  = w & 3;                         // 4 N-waves

    // ---- A: per-lane global->reg addressing (no LDS, no swizzle) ----
    // frag (mi): lane l reads A[bm*256 + wm*128 + mi*16 + (l&15)][k + (l>>4)*16], 16 B
    const char* Agl = (const char*)A + (size_t)(bm * 256) * 4096;
    int aoff[8];
#pragma unroll
    for (int mi = 0; mi < 8; ++mi)
        aoff[mi] = (wm * 128 + mi * 16 + (l & 15)) * 4096 + (l >> 4) * 16;

    // ---- B staging (inverse-permuted global source, linear LDS dest; r8/r9-verified) ----
    const int lin8 = (l & 7) ^ (l >> 3);
    const int sr2  = (l >> 3) * 2 + (lin8 >> 2);   // source row within 16-row chunk
    const int sc   = (lin8 & 3) * 16;              // source col byte within 64B k-slice
    const char* BsrcT = (const char*)Bt + (size_t)(bn * 256 + 32 * w + sr2) * 4096 + sc;
    const int wB = w * 2048;                       // wave's 2-chunk slice (rows 32w..32w+31)

    // ---- B frag read addressing (swizzled; rsl per-thread const) ----
    const int rsl  = ((l >> 4) + 4 * (l & 1)) ^ ((l >> 1) & 7);
    const int b_rd = wn * 4096 + ((l & 15) >> 1) * 128 + rsl * 16;   // + ni*1024

    int4v acc[8][4] = {};
    int4v aX[8], aY[8];     // A double-buffer (static names, rule 20)
    int4v bf[4];

    // ---- prologue: A(0)->aX; stage B(0)->buf0, B(1)->buf1; land A(0),B(0) ----
#pragma unroll
    for (int mi = 0; mi < 8; ++mi)
        aX[mi] = *(const int4v*)(Agl + aoff[mi]);
    STAGE_B(0, 0);
    STAGE_B(16384, 64);
    WAIT_VM2();                                    // B(1)'s 2 stay in flight
    BAR();

    // ---- main loop: 16 macro-iters x 4 K-tiles (64 total); buffers rotate mod 4 ----
    for (int m4 = 0; m4 < 16; ++m4) {
        const int t4 = m4 * 4;
        BODY(t4 + 0,     0, 32768, aX, aY);
        BODY(t4 + 1, 16384, 49152, aY, aX);
        BODY(t4 + 2, 32768,     0, aX, aY);
        BODY(t4 + 3, 49152, 16384, aY, aX);
    }
    asm volatile("s_waitcnt vmcnt(0) lgkmcnt(0)" ::: "memory");   // drain before epilogue

    // ---- epilogue: dequant + bias + ReLU + f32 store (C/D: col=l&15, row=(l>>4)*4+r) ----
    const int col0 = bn * 256 + wn * 64 + (l & 15);
    const int row0 = bm * 256 + wm * 128 + ((l >> 4) << 2);
    float bn4[4];
#pragma unroll
    for (int n = 0; n < 4; ++n) bn4[n] = bias[col0 + n * 16];
#pragma unroll
    for (int m = 0; m < 8; ++m) {
#pragma unroll
        for (int r = 0; r < 4; ++r) {
            const int   grow = row0 + m * 16 + r;
            const float ivs  = inv_s[grow];
#pragma unroll
            for (int n = 0; n < 4; ++n) {
                const float v = (float)acc[m][n][r] * ivs + bn4[n];
                C[(size_t)grow * 4096 + (col0 + n * 16)] = v > 0.f ? v : 0.f;
            }
        }
    }
}

// ---------------- fallback (only if ws too small): slow but correct ----------------
__global__ __launch_bounds__(256) void fallback_kernel(const float* __restrict__ X,
                                                       const float* __restrict__ W,
                                                       const float* __restrict__ b,
                                                       float* __restrict__ out) {
    __shared__ float xs[16][16];
    __shared__ float ws[16][17];
    const int row = blockIdx.y * 16 + threadIdx.y;
    const int col = blockIdx.x * 16 + threadIdx.x;
    float acc = 0.f;
    for (int k0 = 0; k0 < 4096; k0 += 16) {
        xs[threadIdx.y][threadIdx.x] = X[(size_t)row * 4096 + k0 + threadIdx.x];
        float w = W[(size_t)(k0 + threadIdx.y) * 4096 + col];
        ws[threadIdx.y][threadIdx.x] = (w >= 0.f) ? 1.f : -1.f;
        __syncthreads();
#pragma unroll
        for (int kk = 0; kk < 16; ++kk) acc += xs[threadIdx.y][kk] * ws[kk][threadIdx.x];
        __syncthreads();
    }
    const float v = acc + b[col];
    out[(size_t)row * 4096 + col] = v > 0.f ? v : 0.f;
}

extern "C" void kernel_launch(void* const* d_in, const int* in_sizes, int n_in,
                              void* d_out, int out_size, void* d_ws, size_t ws_size,
                              hipStream_t stream) {
    const float* x = (const float*)d_in[0];
    const float* W = (const float*)d_in[1];
    const float* b = (const float*)d_in[2];
    float* out = (float*)d_out;

    const size_t need = (size_t)32 * 1024 * 1024 + 64 * 1024;   // 2x16MB i8 + 16KB scales
    if (ws_size < need) {
        fallback_kernel<<<dim3(256, 256), dim3(16, 16), 0, stream>>>(x, W, b, out);
        return;
    }

    i8*    Xq  = (i8*)d_ws;                                     // i8 x, [4096][4096]
    i8*    Wt  = Xq + (size_t)4096 * 4096;                      // i8 sign(W)^T, [N][K]
    float* ivs = (float*)(Xq + (size_t)2 * 4096 * 4096);        // per-row inv scale

    quant_x_kernel<<<dim3(4096), dim3(256), 0, stream>>>(x, Xq, ivs);
    conv_w_kernel<<<dim3(4096), dim3(256), 0, stream>>>(W, Wt);
    gemm_bin_kernel<<<dim3(256), dim3(512), 0, stream>>>(Xq, Wt, b, ivs, out);
}

// Round 11
// 105.943 us; speedup vs baseline: 1.8145x; 1.8145x over previous
//
#include <hip/hip_runtime.h>
#include <hip/hip_bf16.h>

typedef unsigned short u16;
typedef signed char i8;
typedef __attribute__((ext_vector_type(4)))  int int4v;    // 16 x i8 MFMA A/B frag
typedef __attribute__((ext_vector_type(16))) int int16v;   // 32x32 MFMA C/D frag

#define GLOBAL_AS __attribute__((address_space(1)))
#define LDS_AS    __attribute__((address_space(3)))

__device__ __forceinline__ void gload_lds16(const void* g, void* l) {
    // 16B/lane direct global->LDS (dest = wave-uniform base + lane*16)
    __builtin_amdgcn_global_load_lds((const GLOBAL_AS unsigned int*)g,
                                     (LDS_AS unsigned int*)l, 16, 0, 0);
}

// ---------------- x: f32 -> i8, per-row symmetric quant; inv_s[row] = rowmax/127 ----------------
__global__ __launch_bounds__(256) void quant_x_kernel(const float* __restrict__ X,
                                                      i8* __restrict__ Xq,
                                                      float* __restrict__ inv_s) {
    const int row = blockIdx.x;
    const int t   = threadIdx.x;
    const float4* src = (const float4*)(X + (size_t)row * 4096 + t * 16);
    float4 v0 = src[0], v1 = src[1], v2 = src[2], v3 = src[3];
    float vals[16] = {v0.x, v0.y, v0.z, v0.w, v1.x, v1.y, v1.z, v1.w,
                      v2.x, v2.y, v2.z, v2.w, v3.x, v3.y, v3.z, v3.w};
    float m = 0.f;
#pragma unroll
    for (int j = 0; j < 16; ++j) m = fmaxf(m, fabsf(vals[j]));
#pragma unroll
    for (int off = 32; off; off >>= 1) m = fmaxf(m, __shfl_xor(m, off));
    __shared__ float sm[4];
    if ((t & 63) == 0) sm[t >> 6] = m;
    __syncthreads();
    m = fmaxf(fmaxf(sm[0], sm[1]), fmaxf(sm[2], sm[3]));
    const float s = (m > 0.f) ? 127.0f / m : 0.f;
    uint4 packed;
    unsigned int* pw = (unsigned int*)&packed;
#pragma unroll
    for (int g = 0; g < 4; ++g) {
        unsigned int wd = 0;
#pragma unroll
        for (int j = 0; j < 4; ++j) {
            int q = (int)rintf(vals[g * 4 + j] * s);   // |q| <= 127 by construction
            wd |= ((unsigned int)(q & 255)) << (8 * j);
        }
        pw[g] = wd;
    }
    ((uint4*)(Xq + (size_t)row * 4096))[t] = packed;
    if (t == 0) inv_s[row] = m * (1.0f / 127.0f);
}

// ---------------- W: f32 [K][N] -> sign i8 (+-1), transposed to [N][K] ----------------
__global__ __launch_bounds__(256) void conv_w_kernel(const float* __restrict__ W,
                                                     i8* __restrict__ Wt) {
    __shared__ __attribute__((aligned(16))) i8 tile[64][80];   // [n_local][k_local], 80 = 5*16
    const int t  = threadIdx.x;
    const int k0 = (blockIdx.x & 63) * 64;
    const int n0 = (blockIdx.x >> 6) * 64;
#pragma unroll
    for (int i = 0; i < 4; ++i) {
        const int r = i * 16 + (t >> 4);      // k_local
        const int c = (t & 15) * 4;           // n_local
        float4 v = *(const float4*)&W[(size_t)(k0 + r) * 4096 + n0 + c];
        tile[c + 0][r] = (v.x >= 0.f) ? 1 : -1;
        tile[c + 1][r] = (v.y >= 0.f) ? 1 : -1;
        tile[c + 2][r] = (v.z >= 0.f) ? 1 : -1;
        tile[c + 3][r] = (v.w >= 0.f) ? 1 : -1;
    }
    __syncthreads();
    const int r = t >> 2;                     // n_local 0..63
    const int c = (t & 3) * 16;               // k_local 16B chunk
    *(int4*)&Wt[(size_t)(n0 + r) * 4096 + k0 + c] = *(const int4*)&tile[r][c];
}

// ---------------- GEMM: i8 256x256, BK=64, 4 waves x 128x128, mfma 32x32x32 (r11) ----------------
// r6-r10 evidence: time = LDS-pipe + matrix-pipe SUM in every schedule. This round reduces
// both demands: (1) wave tile 128x128 (4 waves instead of 8) -> frag-read traffic 96->64KB
// per K-64 (each frag byte feeds 2x FLOPs); (2) mfma_i32_32x32x32_i8 (4404 vs 3944 TOPS).
// Memory engine: r9's verified 3-buffer rotation + stored LDS layout + staging formulas,
// byte-identical. Only the frag READ addressing changes (32-row pattern): slot =
// ((l>>5)+4(l&1)) ^ ((l>>1)&7); bank census = 8 lanes per 16B slot (uniform, conflict-free).
// 1 wave/SIMD: intra-wave ILP overlaps ds_read issue with MFMA execution; acc 256 VGPR.

#define BAR()        __builtin_amdgcn_s_barrier()
#define LGKM0M()     asm volatile("s_waitcnt lgkmcnt(0)" ::: "memory")
#define WAIT_VM8()   asm volatile("s_waitcnt vmcnt(8)" ::: "memory")

// stage one full K-tile (A 256x64B = 16KB + B 16KB): 8 x gload_lds per thread.
// Wave w stages A rows 64w..64w+63 (chunks j=0..3) and B rows likewise; linear dest.
#define STAGE_TILE(base, koff)                                                      \
    do {                                                                            \
        _Pragma("unroll") for (int j = 0; j < 4; ++j)                               \
            gload_lds16(AsrcT + j * 65536 + (koff), lds + (base) + wS + j * 1024);  \
        _Pragma("unroll") for (int j = 0; j < 4; ++j)                               \
            gload_lds16(BsrcT + j * 65536 + (koff), lds + (base) + 16384 + wS + j * 1024); \
    } while (0)

__global__ __launch_bounds__(256, 1) void gemm_bin_kernel(const i8* __restrict__ A,
                                                          const i8* __restrict__ Bt,
                                                          const float* __restrict__ bias,
                                                          const float* __restrict__ inv_s,
                                                          float* __restrict__ C) {
    __shared__ __attribute__((aligned(1024))) char lds[98304];   // 3 bufs x (A 16K + B 16K)

    const int bid = blockIdx.x;
    const int swz = (bid & 7) * 32 + (bid >> 3);   // XCD-aware, bijective (256 % 8 == 0)
    const int bm  = swz >> 4;                      // 16x16 tiles of 256
    const int bn  = swz & 15;

    const int tid = threadIdx.x;
    const int w   = tid >> 6;                      // 4 waves
    const int l   = tid & 63;
    const int wm  = w >> 1;                        // 2x2 wave grid, wave tile 128x128
    const int wn  = w & 1;

    // ---- staging addressing (r8/r9-verified formulas; stored layout unchanged) ----
    // Lane l writes linear slot l&7 at super-row l>>3 of its 1KB chunk; that slot holds
    // logical lin8 = (l&7)^(l>>3) -> source row offset sr2, source col sc.
    const int lin8 = (l & 7) ^ (l >> 3);
    const int sr2  = (l >> 3) * 2 + (lin8 >> 2);
    const int sc   = (lin8 & 3) * 16;
    const char* AsrcT = (const char*)A  + (size_t)(bm * 256 + w * 64 + sr2) * 4096 + sc;
    const char* BsrcT = (const char*)Bt + (size_t)(bn * 256 + w * 64 + sr2) * 4096 + sc;
    const int wS = w * 4096;                       // wave's 4-chunk slice within a region

    // ---- frag read addressing (32-row pattern for 32x32x32) ----
    // logical: row r = (l&31) + 32*mi (+128*wm), k-16B-slice c = ks*2 + (l>>5).
    // stored slot = (c + 4*(r&1)) ^ ((r>>1)&7); folds to per-thread const, ks via XOR bit5.
    const int rd_sl    = ((((l >> 5) + 4 * (l & 1)) ^ ((l >> 1) & 7)) << 4);
    const int row_part = ((l >> 1) & 15) * 128;
    const int a_rd = wm * 8192 + row_part + rd_sl;            // + mi*2048, ^ (ks*32)
    const int b_rd = 16384 + wn * 8192 + row_part + rd_sl;    // + nj*2048, ^ (ks*32)

    int16v acc[4][4] = {};   // 16 x 32x32 tiles = 256 VGPR
    int4v  af[4], bf[4];

    // ---- prologue: stage tile0->buf0, tile1->buf1; land tile0 (tile1's 8 in flight) ----
    STAGE_TILE(0, 0);
    STAGE_TILE(32768, 64);
    WAIT_VM8();
    BAR();

    // ---- main loop: 64 K-tiles of 64 i8; 3-buffer rotation, 1 barrier + 1 fence each ----
    int rb = 0;          // buffer holding tile t
    int sb = 65536;      // stage target (read at t-1, free since last barrier)
    for (int t = 0; t < 64; ++t) {
        const int koff2 = ((t + 2) & 63) * 64;

        STAGE_TILE(sb, koff2);                     // DMA issue early; lands 2 iters later

#pragma unroll
        for (int ks = 0; ks < 2; ++ks) {
#pragma unroll
            for (int mi = 0; mi < 4; ++mi)
                af[mi] = *(const int4v*)(lds + ((rb + a_rd + mi * 2048) ^ (ks * 32)));
#pragma unroll
            for (int nj = 0; nj < 4; ++nj)
                bf[nj] = *(const int4v*)(lds + ((rb + b_rd + nj * 2048) ^ (ks * 32)));
            __builtin_amdgcn_s_setprio(1);
#pragma unroll
            for (int mi = 0; mi < 4; ++mi)
#pragma unroll
                for (int nj = 0; nj < 4; ++nj)
                    acc[mi][nj] = __builtin_amdgcn_mfma_i32_32x32x32_i8(af[mi], bf[nj],
                                                                        acc[mi][nj], 0, 0, 0);
            __builtin_amdgcn_s_setprio(0);
        }

        WAIT_VM8();                                // tile t+1 landed (t+2's 8 in flight)
        LGKM0M();                                  // own ds_reads drained (WAR-safe vs DMA)
        BAR();                                     // iteration boundary: frees buf rb
        sb = rb;
        rb = (rb == 65536) ? 0 : rb + 32768;
    }
    asm volatile("s_waitcnt vmcnt(0) lgkmcnt(0)" ::: "memory");   // drain before epilogue

    // ---- epilogue: dequant + bias + ReLU + f32 store ----
    // 32x32 C/D layout (m74/m101, dtype-independent): col = l&31,
    // row = (reg&3) + 8*(reg>>2) + 4*(l>>5).
    const int col0 = bn * 256 + wn * 128 + (l & 31);
    const int row0 = bm * 256 + wm * 128 + 4 * (l >> 5);
    float bi4[4];
#pragma unroll
    for (int nj = 0; nj < 4; ++nj) bi4[nj] = bias[col0 + nj * 32];
#pragma unroll
    for (int mi = 0; mi < 4; ++mi) {
#pragma unroll
        for (int reg = 0; reg < 16; ++reg) {
            const int   grow = row0 + mi * 32 + (reg & 3) + 8 * (reg >> 2);
            const float ivs  = inv_s[grow];
            float* crow = C + (size_t)grow * 4096 + col0;
#pragma unroll
            for (int nj = 0; nj < 4; ++nj) {
                const float v = (float)acc[mi][nj][reg] * ivs + bi4[nj];
                crow[nj * 32] = v > 0.f ? v : 0.f;
            }
        }
    }
}

// ---------------- fallback (only if ws too small): slow but correct ----------------
__global__ __launch_bounds__(256) void fallback_kernel(const float* __restrict__ X,
                                                       const float* __restrict__ W,
                                                       const float* __restrict__ b,
                                                       float* __restrict__ out) {
    __shared__ float xs[16][16];
    __shared__ float ws[16][17];
    const int row = blockIdx.y * 16 + threadIdx.y;
    const int col = blockIdx.x * 16 + threadIdx.x;
    float acc = 0.f;
    for (int k0 = 0; k0 < 4096; k0 += 16) {
        xs[threadIdx.y][threadIdx.x] = X[(size_t)row * 4096 + k0 + threadIdx.x];
        float w = W[(size_t)(k0 + threadIdx.y) * 4096 + col];
        ws[threadIdx.y][threadIdx.x] = (w >= 0.f) ? 1.f : -1.f;
        __syncthreads();
#pragma unroll
        for (int kk = 0; kk < 16; ++kk) acc += xs[threadIdx.y][kk] * ws[kk][threadIdx.x];
        __syncthreads();
    }
    const float v = acc + b[col];
    out[(size_t)row * 4096 + col] = v > 0.f ? v : 0.f;
}

extern "C" void kernel_launch(void* const* d_in, const int* in_sizes, int n_in,
                              void* d_out, int out_size, void* d_ws, size_t ws_size,
                              hipStream_t stream) {
    const float* x = (const float*)d_in[0];
    const float* W = (const float*)d_in[1];
    const float* b = (const float*)d_in[2];
    float* out = (float*)d_out;

    const size_t need = (size_t)32 * 1024 * 1024 + 64 * 1024;   // 2x16MB i8 + 16KB scales
    if (ws_size < need) {
        fallback_kernel<<<dim3(256, 256), dim3(16, 16), 0, stream>>>(x, W, b, out);
        return;
    }

    i8*    Xq  = (i8*)d_ws;                                     // i8 x, [4096][4096]
    i8*    Wt  = Xq + (size_t)4096 * 4096;                      // i8 sign(W)^T, [N][K]
    float* ivs = (float*)(Xq + (size_t)2 * 4096 * 4096);        // per-row inv scale

    quant_x_kernel<<<dim3(4096), dim3(256), 0, stream>>>(x, Xq, ivs);
    conv_w_kernel<<<dim3(4096), dim3(256), 0, stream>>>(W, Wt);
    gemm_bin_kernel<<<dim3(256), dim3(256), 0, stream>>>(Xq, Wt, b, ivs, out);
}

// Round 13
// 95.580 us; speedup vs baseline: 2.0113x; 1.1084x over previous
//
#include <hip/hip_runtime.h>
#include <hip/hip_bf16.h>

typedef unsigned short u16;
typedef signed char i8;
typedef __attribute__((ext_vector_type(4))) int   int4v;   // 16 x i8 MFMA A/B frag, or i32x4 C/D
typedef __attribute__((ext_vector_type(4))) float f32x4;

#define GLOBAL_AS __attribute__((address_space(1)))
#define LDS_AS    __attribute__((address_space(3)))

__device__ __forceinline__ void gload_lds16(const void* g, void* l) {
    // 16B/lane direct global->LDS (dest = wave-uniform base + lane*16)
    __builtin_amdgcn_global_load_lds((const GLOBAL_AS unsigned int*)g,
                                     (LDS_AS unsigned int*)l, 16, 0, 0);
}

// ---------------- x: f32 -> i8, per-row symmetric quant; inv_s[row] = rowmax/127 ----------------
__global__ __launch_bounds__(256) void quant_x_kernel(const float* __restrict__ X,
                                                      i8* __restrict__ Xq,
                                                      float* __restrict__ inv_s) {
    const int row = blockIdx.x;
    const int t   = threadIdx.x;
    const float4* src = (const float4*)(X + (size_t)row * 4096 + t * 16);
    float4 v0 = src[0], v1 = src[1], v2 = src[2], v3 = src[3];
    float vals[16] = {v0.x, v0.y, v0.z, v0.w, v1.x, v1.y, v1.z, v1.w,
                      v2.x, v2.y, v2.z, v2.w, v3.x, v3.y, v3.z, v3.w};
    float m = 0.f;
#pragma unroll
    for (int j = 0; j < 16; ++j) m = fmaxf(m, fabsf(vals[j]));
#pragma unroll
    for (int off = 32; off; off >>= 1) m = fmaxf(m, __shfl_xor(m, off));
    __shared__ float sm[4];
    if ((t & 63) == 0) sm[t >> 6] = m;
    __syncthreads();
    m = fmaxf(fmaxf(sm[0], sm[1]), fmaxf(sm[2], sm[3]));
    const float s = (m > 0.f) ? 127.0f / m : 0.f;
    uint4 packed;
    unsigned int* pw = (unsigned int*)&packed;
#pragma unroll
    for (int g = 0; g < 4; ++g) {
        unsigned int wd = 0;
#pragma unroll
        for (int j = 0; j < 4; ++j) {
            int q = (int)rintf(vals[g * 4 + j] * s);   // |q| <= 127 by construction
            wd |= ((unsigned int)(q & 255)) << (8 * j);
        }
        pw[g] = wd;
    }
    ((uint4*)(Xq + (size_t)row * 4096))[t] = packed;
    if (t == 0) inv_s[row] = m * (1.0f / 127.0f);
}

// ---------------- W: f32 [K][N] -> sign i8 (+-1), transposed to [N][K] ----------------
__global__ __launch_bounds__(256) void conv_w_kernel(const float* __restrict__ W,
                                                     i8* __restrict__ Wt) {
    __shared__ __attribute__((aligned(16))) i8 tile[64][80];   // [n_local][k_local], 80 = 5*16
    const int t  = threadIdx.x;
    const int k0 = (blockIdx.x & 63) * 64;
    const int n0 = (blockIdx.x >> 6) * 64;
#pragma unroll
    for (int i = 0; i < 4; ++i) {
        const int r = i * 16 + (t >> 4);      // k_local
        const int c = (t & 15) * 4;           // n_local
        float4 v = *(const float4*)&W[(size_t)(k0 + r) * 4096 + n0 + c];
        tile[c + 0][r] = (v.x >= 0.f) ? 1 : -1;
        tile[c + 1][r] = (v.y >= 0.f) ? 1 : -1;
        tile[c + 2][r] = (v.z >= 0.f) ? 1 : -1;
        tile[c + 3][r] = (v.w >= 0.f) ? 1 : -1;
    }
    __syncthreads();
    const int r = t >> 2;                     // n_local 0..63
    const int c = (t & 3) * 16;               // k_local 16B chunk
    *(int4*)&Wt[(size_t)(n0 + r) * 4096 + k0 + c] = *(const int4*)&tile[r][c];
}

// ---------------- GEMM: i8 256x256, BK=64, wave-group ping-pong (r13 = r12 + coverage fix) ----------------
// r12 bug: E staged tiles t+4, O staged t+3, prologue 0-2 -> tile 3's E-half never staged.
// Fix: BOTH groups stage share(t+3) (disjoint row halves, w-indexed). Ledger (re-derived):
//   per-wave: prologue 12 loads, VM8 retires t0; each phase's VM4 retires the share staged
//   2 iters ago = own-half of tile t+1, exactly before that tile is read.
//   O reads t at A(t):   O-half retired A(t-1) vm4; E-half retired E's B(t-1) vm4 + BAR. OK
//   E reads t+1 at B(t): E-half retired this vm4;   O-half retired O's A(t) vm4 + BAR.   OK
//   WAR: stages target buf (t-1)&3; its readers LGKM0-drained >=1 barrier earlier.       OK
//   Tail: stages wrap to dead buffers; B(63)'s read never consumed.                      OK
// Roles: phase A(t): O reads frags(t)+stages(t+3) while E MFMAs(t); phase B(t): E reads
// frags(t+1)+stages(t+3) while O MFMAs(t). Every phase: 4 waves on LDS pipe + 1 wave/SIMD
// on matrix pipe (m114 overlap). Addressing = r9 verbatim (0 conflicts, verified).

#define BAR()        __builtin_amdgcn_s_barrier()
#define LGKM0M()     asm volatile("s_waitcnt lgkmcnt(0)" ::: "memory")
#define WAIT_VM4()   asm volatile("s_waitcnt vmcnt(4)" ::: "memory")
#define WAIT_VM8()   asm volatile("s_waitcnt vmcnt(8)" ::: "memory")

// stage this wave's rows (32w..32w+31) of one K-tile (4 x gload_lds, 4KB)
#define STAGE_TILE(base, koff)                                                      \
    do {                                                                            \
        gload_lds16(AsrcT + (koff),         lds + (base) + wA);                     \
        gload_lds16(AsrcT + 65536 + (koff), lds + (base) + wA + 1024);              \
        gload_lds16(BsrcT + (koff),         lds + (base) + 16384 + wA);             \
        gload_lds16(BsrcT + 65536 + (koff), lds + (base) + 16384 + wA + 1024);      \
    } while (0)

#define READ_FRAGS(base)                                                            \
    do {                                                                            \
        _Pragma("unroll") for (int mi = 0; mi < 8; ++mi)                            \
            af[mi] = *(const int4v*)(lds + (base) + a_rd + mi * 1024);              \
        _Pragma("unroll") for (int ni = 0; ni < 4; ++ni)                            \
            bf[ni] = *(const int4v*)(lds + (base) + b_rd + ni * 1024);              \
    } while (0)

#define MFMA_ALL()                                                                  \
    do {                                                                            \
        __builtin_amdgcn_s_setprio(1);                                              \
        _Pragma("unroll") for (int mi = 0; mi < 8; ++mi)                            \
        _Pragma("unroll") for (int ni = 0; ni < 4; ++ni)                            \
            acc[mi][ni] = __builtin_amdgcn_mfma_i32_16x16x64_i8(af[mi], bf[ni],     \
                                                                acc[mi][ni], 0, 0, 0); \
        __builtin_amdgcn_s_setprio(0);                                              \
    } while (0)

__global__ __launch_bounds__(512, 2) void gemm_bin_kernel(const i8* __restrict__ A,
                                                          const i8* __restrict__ Bt,
                                                          const float* __restrict__ bias,
                                                          const float* __restrict__ inv_s,
                                                          float* __restrict__ C) {
    __shared__ __attribute__((aligned(1024))) char lds[131072];   // 4 bufs x (A 16K + B 16K)

    const int bid = blockIdx.x;
    const int swz = (bid & 7) * 32 + (bid >> 3);   // XCD-aware, bijective (256 % 8 == 0)
    const int bm  = swz >> 4;                      // 16x16 tiles of 256
    const int bn  = swz & 15;

    const int tid = threadIdx.x;
    const int w   = tid >> 6;
    const int l   = tid & 63;
    const int wm  = w >> 2;                        // 2 M-waves; E group = wm 0, O = wm 1
    const int wn  = w & 3;                         // 4 N-waves
    const bool isE = (w < 4);                      // one E + one O wave per SIMD (w&3)

    // ---- staging addressing (r9 verbatim; inverse-permuted source, linear LDS dest) ----
    const int lin8 = (l & 7) ^ (l >> 3);
    const int sr2  = (l >> 3) * 2 + (lin8 >> 2);
    const int sc   = (lin8 & 3) * 16;
    const char* AsrcT = (const char*)A  + (size_t)(bm * 256 + 32 * w + sr2) * 4096 + sc;
    const char* BsrcT = (const char*)Bt + (size_t)(bn * 256 + 32 * w + sr2) * 4096 + sc;
    const int wA = w * 2048;                       // wave's 2-chunk slice within a region

    // ---- frag read addressing (r9 verbatim; swizzled, 0 conflicts) ----
    const int rsl  = ((l >> 4) + 4 * (l & 1)) ^ ((l >> 1) & 7);
    const int a_rd = wm * 8192 + ((l & 15) >> 1) * 128 + rsl * 16;           // + mi*1024
    const int b_rd = 16384 + wn * 4096 + ((l & 15) >> 1) * 128 + rsl * 16;   // + ni*1024

    int4v acc[8][4] = {};
    int4v af[8], bf[4];

    // ---- prologue: stage t0,t1,t2 (12 gloads/wave); land t0; E pre-reads frags(t0) ----
    STAGE_TILE(0, 0);
    STAGE_TILE(32768, 64);
    STAGE_TILE(65536, 128);
    WAIT_VM8();                                    // t0 landed (t1,t2 shares in flight)
    BAR();
    if (isE) { READ_FRAGS(0); LGKM0M(); }
    BAR();

    // ---- main loop: 64 K-tiles of 64 i8; 2 role-split phases per tile ----
    for (int t = 0; t < 64; ++t) {
        const int bufR  = (t & 3) * 32768;                 // tile t
        const int bufR1 = ((t + 1) & 3) * 32768;           // tile t+1
        const int bufS3 = ((t + 3) & 3) * 32768;           // stage target (both groups)
        const int ko3   = ((t + 3) & 63) * 64;             // wraps to harmless re-stage

        // phase A(t): O reads tile t + stages its half of tile t+3; E MFMAs tile t
        if (!isE) {
            WAIT_VM4();                // retire own share of t+1 (covers E's B(t) read)
            READ_FRAGS(bufR);
            STAGE_TILE(bufS3, ko3);
            LGKM0M();                  // own reads drained (WAR-safe vs future DMA)
        } else {
            MFMA_ALL();                // frags(t) read at B(t-1) / prologue
        }
        BAR();

        // phase B(t): E reads tile t+1 + stages its half of tile t+3; O MFMAs tile t
        if (isE) {
            WAIT_VM4();                // retire own share of t+1 (just before reading it)
            READ_FRAGS(bufR1);         // t=63: dummy read, never consumed
            STAGE_TILE(bufS3, ko3);
            LGKM0M();
        } else {
            MFMA_ALL();                // frags(t) read at A(t)
        }
        BAR();
    }
    asm volatile("s_waitcnt vmcnt(0) lgkmcnt(0)" ::: "memory");   // drain before epilogue

    // ---- epilogue: dequant + bias + ReLU + f32 store (C/D: col=l&15, row=(l>>4)*4+r) ----
    const int col0 = bn * 256 + wn * 64 + (l & 15);
    const int row0 = bm * 256 + wm * 128 + ((l >> 4) << 2);
    float bn4[4];
#pragma unroll
    for (int n = 0; n < 4; ++n) bn4[n] = bias[col0 + n * 16];
#pragma unroll
    for (int m = 0; m < 8; ++m) {
#pragma unroll
        for (int r = 0; r < 4; ++r) {
            const int   grow = row0 + m * 16 + r;
            const float ivs  = inv_s[grow];
#pragma unroll
            for (int n = 0; n < 4; ++n) {
                const float v = (float)acc[m][n][r] * ivs + bn4[n];
                C[(size_t)grow * 4096 + (col0 + n * 16)] = v > 0.f ? v : 0.f;
            }
        }
    }
}

// ---------------- fallback (only if ws too small): slow but correct ----------------
__global__ __launch_bounds__(256) void fallback_kernel(const float* __restrict__ X,
                                                       const float* __restrict__ W,
                                                       const float* __restrict__ b,
                                                       float* __restrict__ out) {
    __shared__ float xs[16][16];
    __shared__ float ws[16][17];
    const int row = blockIdx.y * 16 + threadIdx.y;
    const int col = blockIdx.x * 16 + threadIdx.x;
    float acc = 0.f;
    for (int k0 = 0; k0 < 4096; k0 += 16) {
        xs[threadIdx.y][threadIdx.x] = X[(size_t)row * 4096 + k0 + threadIdx.x];
        float w = W[(size_t)(k0 + threadIdx.y) * 4096 + col];
        ws[threadIdx.y][threadIdx.x] = (w >= 0.f) ? 1.f : -1.f;
        __syncthreads();
#pragma unroll
        for (int kk = 0; kk < 16; ++kk) acc += xs[threadIdx.y][kk] * ws[kk][threadIdx.x];
        __syncthreads();
    }
    const float v = acc + b[col];
    out[(size_t)row * 4096 + col] = v > 0.f ? v : 0.f;
}

extern "C" void kernel_launch(void* const* d_in, const int* in_sizes, int n_in,
                              void* d_out, int out_size, void* d_ws, size_t ws_size,
                              hipStream_t stream) {
    const float* x = (const float*)d_in[0];
    const float* W = (const float*)d_in[1];
    const float* b = (const float*)d_in[2];
    float* out = (float*)d_out;

    const size_t need = (size_t)32 * 1024 * 1024 + 64 * 1024;   // 2x16MB i8 + 16KB scales
    if (ws_size < need) {
        fallback_kernel<<<dim3(256, 256), dim3(16, 16), 0, stream>>>(x, W, b, out);
        return;
    }

    i8*    Xq  = (i8*)d_ws;                                     // i8 x, [4096][4096]
    i8*    Wt  = Xq + (size_t)4096 * 4096;                      // i8 sign(W)^T, [N][K]
    float* ivs = (float*)(Xq + (size_t)2 * 4096 * 4096);        // per-row inv scale

    quant_x_kernel<<<dim3(4096), dim3(256), 0, stream>>>(x, Xq, ivs);
    conv_w_kernel<<<dim3(4096), dim3(256), 0, stream>>>(W, Wt);
    gemm_bin_kernel<<<dim3(256), dim3(512), 0, stream>>>(Xq, Wt, b, ivs, out);
}

// Round 14
// 95.470 us; speedup vs baseline: 2.0136x; 1.0012x over previous
//
#include <hip/hip_runtime.h>
#include <hip/hip_bf16.h>

typedef unsigned short u16;
typedef signed char i8;
typedef __attribute__((ext_vector_type(4))) int   int4v;   // 16 x i8 MFMA A/B frag, or i32x4 C/D
typedef __attribute__((ext_vector_type(4))) float f32x4;

#define GLOBAL_AS __attribute__((address_space(1)))
#define LDS_AS    __attribute__((address_space(3)))

__device__ __forceinline__ void gload_lds16(const void* g, void* l) {
    // 16B/lane direct global->LDS (dest = wave-uniform base + lane*16)
    __builtin_amdgcn_global_load_lds((const GLOBAL_AS unsigned int*)g,
                                     (LDS_AS unsigned int*)l, 16, 0, 0);
}

// ---------------- fused pre-pass: one dispatch, split grid (r14) ----------------
// blocks 0..4095:    x row quant  f32 -> i8 (per-row symmetric, inv_s[row] = rowmax/127)
// blocks 4096..8191: W 64x64 tile f32 [K][N] -> sign i8 (+-1) transposed to [N][K]
// Bodies verbatim from the r6-r13-verified quant_x_kernel / conv_w_kernel; fusing removes
// one dispatch boundary and lets the two independent BW-bound streams share the machine.
__global__ __launch_bounds__(256) void pre_kernel(const float* __restrict__ X,
                                                  const float* __restrict__ W,
                                                  i8* __restrict__ Xq,
                                                  i8* __restrict__ Wt,
                                                  float* __restrict__ inv_s) {
    __shared__ float sm[4];
    __shared__ __attribute__((aligned(16))) i8 tile[64][80];   // [n_local][k_local]
    const int bid = blockIdx.x;
    const int t   = threadIdx.x;

    if (bid < 4096) {
        // ---- quant x row ----
        const int row = bid;
        const float4* src = (const float4*)(X + (size_t)row * 4096 + t * 16);
        float4 v0 = src[0], v1 = src[1], v2 = src[2], v3 = src[3];
        float vals[16] = {v0.x, v0.y, v0.z, v0.w, v1.x, v1.y, v1.z, v1.w,
                          v2.x, v2.y, v2.z, v2.w, v3.x, v3.y, v3.z, v3.w};
        float m = 0.f;
#pragma unroll
        for (int j = 0; j < 16; ++j) m = fmaxf(m, fabsf(vals[j]));
#pragma unroll
        for (int off = 32; off; off >>= 1) m = fmaxf(m, __shfl_xor(m, off));
        if ((t & 63) == 0) sm[t >> 6] = m;
        __syncthreads();
        m = fmaxf(fmaxf(sm[0], sm[1]), fmaxf(sm[2], sm[3]));
        const float s = (m > 0.f) ? 127.0f / m : 0.f;
        uint4 packed;
        unsigned int* pw = (unsigned int*)&packed;
#pragma unroll
        for (int g = 0; g < 4; ++g) {
            unsigned int wd = 0;
#pragma unroll
            for (int j = 0; j < 4; ++j) {
                int q = (int)rintf(vals[g * 4 + j] * s);   // |q| <= 127 by construction
                wd |= ((unsigned int)(q & 255)) << (8 * j);
            }
            pw[g] = wd;
        }
        ((uint4*)(Xq + (size_t)row * 4096))[t] = packed;
        if (t == 0) inv_s[row] = m * (1.0f / 127.0f);
    } else {
        // ---- binarize + transpose W tile ----
        const int cb = bid - 4096;
        const int k0 = (cb & 63) * 64;
        const int n0 = (cb >> 6) * 64;
#pragma unroll
        for (int i = 0; i < 4; ++i) {
            const int r = i * 16 + (t >> 4);      // k_local
            const int c = (t & 15) * 4;           // n_local
            float4 v = *(const float4*)&W[(size_t)(k0 + r) * 4096 + n0 + c];
            tile[c + 0][r] = (v.x >= 0.f) ? 1 : -1;
            tile[c + 1][r] = (v.y >= 0.f) ? 1 : -1;
            tile[c + 2][r] = (v.z >= 0.f) ? 1 : -1;
            tile[c + 3][r] = (v.w >= 0.f) ? 1 : -1;
        }
        __syncthreads();
        const int r = t >> 2;                     // n_local 0..63
        const int c = (t & 3) * 16;               // k_local 16B chunk
        *(int4*)&Wt[(size_t)(n0 + r) * 4096 + k0 + c] = *(const int4*)&tile[r][c];
    }
}

// ---------------- GEMM: i8 256x256, BK=64, wave-group ping-pong (r13 verbatim) ----------------
// Roles: phase A(t): O (w4-7) reads frags(t)+stages its half of (t+3) while E (w0-4) MFMAs(t);
// phase B(t): E reads frags(t+1)+stages half(t+3) while O MFMAs(t). One E + one O wave per
// SIMD -> every phase has 4 waves on the LDS pipe and 1 wave/SIMD on the matrix pipe.
// Ledger (verified r13, passed absmax 3.5, 0 bank conflicts):
//   per-wave VM4 at each read-phase retires own-half of tile t+1 just before it's read;
//   cross-group halves covered by the other group's vm4 + interleaved barrier.
//   WAR: stage target buf (t-1)&3, readers LGKM0-drained >=1 barrier earlier.

#define BAR()        __builtin_amdgcn_s_barrier()
#define LGKM0M()     asm volatile("s_waitcnt lgkmcnt(0)" ::: "memory")
#define WAIT_VM4()   asm volatile("s_waitcnt vmcnt(4)" ::: "memory")
#define WAIT_VM8()   asm volatile("s_waitcnt vmcnt(8)" ::: "memory")

#define STAGE_TILE(base, koff)                                                      \
    do {                                                                            \
        gload_lds16(AsrcT + (koff),         lds + (base) + wA);                     \
        gload_lds16(AsrcT + 65536 + (koff), lds + (base) + wA + 1024);              \
        gload_lds16(BsrcT + (koff),         lds + (base) + 16384 + wA);             \
        gload_lds16(BsrcT + 65536 + (koff), lds + (base) + 16384 + wA + 1024);      \
    } while (0)

#define READ_FRAGS(base)                                                            \
    do {                                                                            \
        _Pragma("unroll") for (int mi = 0; mi < 8; ++mi)                            \
            af[mi] = *(const int4v*)(lds + (base) + a_rd + mi * 1024);              \
        _Pragma("unroll") for (int ni = 0; ni < 4; ++ni)                            \
            bf[ni] = *(const int4v*)(lds + (base) + b_rd + ni * 1024);              \
    } while (0)

#define MFMA_ALL()                                                                  \
    do {                                                                            \
        __builtin_amdgcn_s_setprio(1);                                              \
        _Pragma("unroll") for (int mi = 0; mi < 8; ++mi)                            \
        _Pragma("unroll") for (int ni = 0; ni < 4; ++ni)                            \
            acc[mi][ni] = __builtin_amdgcn_mfma_i32_16x16x64_i8(af[mi], bf[ni],     \
                                                                acc[mi][ni], 0, 0, 0); \
        __builtin_amdgcn_s_setprio(0);                                              \
    } while (0)

__global__ __launch_bounds__(512, 2) void gemm_bin_kernel(const i8* __restrict__ A,
                                                          const i8* __restrict__ Bt,
                                                          const float* __restrict__ bias,
                                                          const float* __restrict__ inv_s,
                                                          float* __restrict__ C) {
    __shared__ __attribute__((aligned(1024))) char lds[131072];   // 4 bufs x (A 16K + B 16K)

    const int bid = blockIdx.x;
    const int swz = (bid & 7) * 32 + (bid >> 3);   // XCD-aware, bijective (256 % 8 == 0)
    const int bm  = swz >> 4;                      // 16x16 tiles of 256
    const int bn  = swz & 15;

    const int tid = threadIdx.x;
    const int w   = tid >> 6;
    const int l   = tid & 63;
    const int wm  = w >> 2;                        // 2 M-waves; E group = wm 0, O = wm 1
    const int wn  = w & 3;                         // 4 N-waves
    const bool isE = (w < 4);                      // one E + one O wave per SIMD (w&3)

    // ---- staging addressing (r9 verbatim; inverse-permuted source, linear LDS dest) ----
    const int lin8 = (l & 7) ^ (l >> 3);
    const int sr2  = (l >> 3) * 2 + (lin8 >> 2);
    const int sc   = (lin8 & 3) * 16;
    const char* AsrcT = (const char*)A  + (size_t)(bm * 256 + 32 * w + sr2) * 4096 + sc;
    const char* BsrcT = (const char*)Bt + (size_t)(bn * 256 + 32 * w + sr2) * 4096 + sc;
    const int wA = w * 2048;                       // wave's 2-chunk slice within a region

    // ---- frag read addressing (r9 verbatim; swizzled, 0 conflicts) ----
    const int rsl  = ((l >> 4) + 4 * (l & 1)) ^ ((l >> 1) & 7);
    const int a_rd = wm * 8192 + ((l & 15) >> 1) * 128 + rsl * 16;           // + mi*1024
    const int b_rd = 16384 + wn * 4096 + ((l & 15) >> 1) * 128 + rsl * 16;   // + ni*1024

    int4v acc[8][4] = {};
    int4v af[8], bf[4];

    // ---- prologue: stage t0,t1,t2 (12 gloads/wave); land t0; E pre-reads frags(t0) ----
    STAGE_TILE(0, 0);
    STAGE_TILE(32768, 64);
    STAGE_TILE(65536, 128);
    WAIT_VM8();                                    // t0 landed (t1,t2 shares in flight)
    BAR();
    if (isE) { READ_FRAGS(0); LGKM0M(); }
    BAR();

    // ---- main loop: 64 K-tiles of 64 i8; 2 role-split phases per tile ----
    for (int t = 0; t < 64; ++t) {
        const int bufR  = (t & 3) * 32768;                 // tile t
        const int bufR1 = ((t + 1) & 3) * 32768;           // tile t+1
        const int bufS3 = ((t + 3) & 3) * 32768;           // stage target (both groups)
        const int ko3   = ((t + 3) & 63) * 64;             // wraps to harmless re-stage

        // phase A(t): O reads tile t + stages its half of tile t+3; E MFMAs tile t
        if (!isE) {
            WAIT_VM4();                // retire own share of t+1 (covers E's B(t) read)
            READ_FRAGS(bufR);
            STAGE_TILE(bufS3, ko3);
            LGKM0M();                  // own reads drained (WAR-safe vs future DMA)
        } else {
            MFMA_ALL();                // frags(t) read at B(t-1) / prologue
        }
        BAR();

        // phase B(t): E reads tile t+1 + stages its half of tile t+3; O MFMAs tile t
        if (isE) {
            WAIT_VM4();                // retire own share of t+1 (just before reading it)
            READ_FRAGS(bufR1);         // t=63: dummy read, never consumed
            STAGE_TILE(bufS3, ko3);
            LGKM0M();
        } else {
            MFMA_ALL();                // frags(t) read at A(t)
        }
        BAR();
    }
    asm volatile("s_waitcnt vmcnt(0) lgkmcnt(0)" ::: "memory");   // drain before epilogue

    // ---- epilogue: dequant + bias + ReLU + f32 store (C/D: col=l&15, row=(l>>4)*4+r) ----
    const int col0 = bn * 256 + wn * 64 + (l & 15);
    const int row0 = bm * 256 + wm * 128 + ((l >> 4) << 2);
    float bn4[4];
#pragma unroll
    for (int n = 0; n < 4; ++n) bn4[n] = bias[col0 + n * 16];
#pragma unroll
    for (int m = 0; m < 8; ++m) {
#pragma unroll
        for (int r = 0; r < 4; ++r) {
            const int   grow = row0 + m * 16 + r;
            const float ivs  = inv_s[grow];
#pragma unroll
            for (int n = 0; n < 4; ++n) {
                const float v = (float)acc[m][n][r] * ivs + bn4[n];
                C[(size_t)grow * 4096 + (col0 + n * 16)] = v > 0.f ? v : 0.f;
            }
        }
    }
}

// ---------------- fallback (only if ws too small): slow but correct ----------------
__global__ __launch_bounds__(256) void fallback_kernel(const float* __restrict__ X,
                                                       const float* __restrict__ W,
                                                       const float* __restrict__ b,
                                                       float* __restrict__ out) {
    __shared__ float xs[16][16];
    __shared__ float ws[16][17];
    const int row = blockIdx.y * 16 + threadIdx.y;
    const int col = blockIdx.x * 16 + threadIdx.x;
    float acc = 0.f;
    for (int k0 = 0; k0 < 4096; k0 += 16) {
        xs[threadIdx.y][threadIdx.x] = X[(size_t)row * 4096 + k0 + threadIdx.x];
        float w = W[(size_t)(k0 + threadIdx.y) * 4096 + col];
        ws[threadIdx.y][threadIdx.x] = (w >= 0.f) ? 1.f : -1.f;
        __syncthreads();
#pragma unroll
        for (int kk = 0; kk < 16; ++kk) acc += xs[threadIdx.y][kk] * ws[kk][threadIdx.x];
        __syncthreads();
    }
    const float v = acc + b[col];
    out[(size_t)row * 4096 + col] = v > 0.f ? v : 0.f;
}

extern "C" void kernel_launch(void* const* d_in, const int* in_sizes, int n_in,
                              void* d_out, int out_size, void* d_ws, size_t ws_size,
                              hipStream_t stream) {
    const float* x = (const float*)d_in[0];
    const float* W = (const float*)d_in[1];
    const float* b = (const float*)d_in[2];
    float* out = (float*)d_out;

    const size_t need = (size_t)32 * 1024 * 1024 + 64 * 1024;   // 2x16MB i8 + 16KB scales
    if (ws_size < need) {
        fallback_kernel<<<dim3(256, 256), dim3(16, 16), 0, stream>>>(x, W, b, out);
        return;
    }

    i8*    Xq  = (i8*)d_ws;                                     // i8 x, [4096][4096]
    i8*    Wt  = Xq + (size_t)4096 * 4096;                      // i8 sign(W)^T, [N][K]
    float* ivs = (float*)(Xq + (size_t)2 * 4096 * 4096);        // per-row inv scale

    pre_kernel<<<dim3(8192), dim3(256), 0, stream>>>(x, W, Xq, Wt, ivs);
    gemm_bin_kernel<<<dim3(256), dim3(512), 0, stream>>>(Xq, Wt, b, ivs, out);
}